// Round 15
// baseline (295.674 us; speedup 1.0000x reference)
//
#include <hip/hip_runtime.h>
#include <hip/hip_cooperative_groups.h>
#include <math.h>

// SANet attention: MFMA flash, LDS-staged K/V (xor-swizzled), 32 q-rows/wave,
// split-K=4, f16 partials. b=4, c=64, HW=4096, fp32 in/out.
//
// R18: R17 reproduced the session best (100.2us; R12 config confirmed).
// Kernel-internal axes all closed; remaining measurable slack is ~14us of
// dispatch gaps across 4 boundaries. This round fuses prep+attn+combine into
// ONE cooperative kernel (grid 512x256, LB(256,2), 32KB LDS = proven
// co-residency) with __threadfence + grid.sync() at the two cross-block
// dependency points. Host falls back to the three R12-proven kernels if
// hipLaunchCooperativeKernel errors (capture-unsupported etc.) -> worst case
// reproduces 100.2.
//
// attn phase = R12 body verbatim (Kl/Vl re-pointed into shared smem, which
// phase 1 aliases for its 16x72 transpose scratch).
//
// Diet (R12-proven): raw v_exp2, m-in-MFMA-C (m_run init 0, combine is
// shift-invariant), permlane P-redistribution, ones-MFMA lsum, left-deep max.
//
// mfma_f32_16x16x32_f16: A[m=lane&15][k=quad*8+j], B[k=quad*8+j][n=lane&15],
// D[m=quad*4+reg][n=lane&15]  (quad = lane>>4).
// S-mfma computes S^T tile (m=k_key, n=q); PV computes O^T (m=c, n=q).
// P redistribution (R7-verified): A_m=pk(sv[m][0],sv[m][1]),
// B_m=pk(sv[m][2],sv[m][3]); (w0,w2)=pl16swap(pl32swap(A_L,A_H)); (w1,w3) from B.

namespace cg = cooperative_groups;

#define Bb 4
#define Cc 64
#define HWs 4096
#define SPLITS 4
#define TILES_PER_SPLIT 16      // 1024 k per split / 64
#define RLOG2E 1.44269504088896340736f
#define DEFER_THR 6.0f

typedef _Float16 half8 __attribute__((ext_vector_type(8)));
typedef _Float16 half4 __attribute__((ext_vector_type(4)));
typedef float floatx4 __attribute__((ext_vector_type(4)));
typedef unsigned uint2v __attribute__((ext_vector_type(2)));

extern "C" __device__ float __ocml_native_exp2_f32(float);
#if defined(__has_builtin) && __has_builtin(__builtin_amdgcn_exp2f)
#define EXP2(x) __builtin_amdgcn_exp2f(x)
#else
#define EXP2(x) __ocml_native_exp2_f32(x)
#endif

// ================= shared phase bodies (device inline) =================

__device__ __forceinline__ void prep_copy_body(int i4, const float* __restrict__ content,
                                               const float* __restrict__ Fst,
                                               float* __restrict__ out,
                                               _Float16* __restrict__ Vt) {
    const float4* c4 = (const float4*)content;
    const float4* v4 = (const float4*)Fst;
    float4* o4 = (float4*)out;
    int b = i4 >> 16, rem = i4 & 65535;
    o4[(size_t)b * 131072 + rem] = c4[i4];            // out batch stride 2*64*4096 f32
    float4 v = v4[i4];
    half4 h;
    h[0] = (_Float16)v.x; h[1] = (_Float16)v.y;
    h[2] = (_Float16)v.z; h[3] = (_Float16)v.w;
    *(half4*)(Vt + (size_t)i4 * 4) = h;
}

__device__ __forceinline__ void combine_body(int idx, const _Float16* __restrict__ Opart,
                                             const float2* __restrict__ ml,
                                             float* __restrict__ out) {
    int q = idx & 4095;
    int c = (idx >> 12) & 63;
    int b = idx >> 18;
    const float2* mlp = ml + ((size_t)b * HWs + q) * SPLITS;
    float2 mls[SPLITS];
    #pragma unroll
    for (int s = 0; s < SPLITS; ++s) mls[s] = mlp[s];
    float M = -INFINITY;
    #pragma unroll
    for (int s = 0; s < SPLITS; ++s) M = fmaxf(M, mls[s].x);
    float l = 0.0f, o = 0.0f;
    #pragma unroll
    for (int s = 0; s < SPLITS; ++s) {
        float wgt = EXP2(mls[s].x - M);
        l += wgt * mls[s].y;
        o += wgt * (float)Opart[(((size_t)s * Bb + b) * Cc + c) * HWs + q];
    }
    out[((size_t)b * 2 * Cc + Cc + c) * HWs + q] = o / l;
}

// ================= fused cooperative kernel =================

__global__ __launch_bounds__(256, 2) void fused_k(const float* __restrict__ content,
                                                  const float* __restrict__ Fs,
                                                  const float* __restrict__ Fst,
                                                  float* __restrict__ out,
                                                  _Float16* __restrict__ Kt,
                                                  _Float16* __restrict__ Vt,
                                                  _Float16* __restrict__ Opart,
                                                  float2* __restrict__ ml) {
    __shared__ _Float16 smem[4 * 4096];               // 32 KB: attn Kl/Vl; prep T alias
    const int tid = threadIdx.x;
    const int bid = blockIdx.x;                       // 0..511

    // ---------- phase 1a: content copy + V f16 convert (2 grid-stride iters)
    #pragma unroll
    for (int it = 0; it < 2; ++it)
        prep_copy_body((it * 512 + bid) * 256 + tid, content, Fst, out, Vt);

    // ---------- phase 1b: Kt transpose (2 tiles per block), T aliases smem
    {
        _Float16 (*T)[72] = reinterpret_cast<_Float16 (*)[72]>(smem);
        #pragma unroll
        for (int it = 0; it < 2; ++it) {
            int e = it * 512 + bid;                   // 0..1023
            int b = e >> 8;
            int hw0 = (e & 255) * 16;
            const float* sb = Fs + (size_t)b * Cc * HWs;
            __syncthreads();                          // protect T reuse across iters
            {
                int c = tid >> 2, x4 = (tid & 3) * 4; // 256 float4 = whole tile
                float4 v = *(const float4*)(sb + (size_t)c * HWs + hw0 + x4);
                T[x4 + 0][c] = (_Float16)v.x;
                T[x4 + 1][c] = (_Float16)v.y;
                T[x4 + 2][c] = (_Float16)v.z;
                T[x4 + 3][c] = (_Float16)v.w;
            }
            __syncthreads();
            if (tid < 128) {
                int row = tid >> 3, g = tid & 7;
                _Float16* db = Kt + (size_t)b * HWs * Cc;
                *(half8*)(db + (size_t)(hw0 + row) * Cc + g * 8) = *(half8*)&T[row][g * 8];
            }
        }
    }

    __threadfence();                                  // Kt/Vt visible device-wide
    cg::this_grid().sync();

    // ---------- phase 2: attn (R12 body; Kl = smem[0..8191], Vl = smem[8192..])
    {
        const int lane = tid & 63;
        const int quad = lane >> 4;
        const int l15  = lane & 15;
        const int w    = tid >> 6;                    // wave 0..3
        const int qg = bid & 31;
        const int b  = (bid >> 5) & 3;
        const int s  = bid >> 7;
        const int k0base = s * TILES_PER_SPLIT * 64;
        const int qA = qg * 128 + w * 32 + l15;       // group 0 q-row
        const int qB = qA + 16;                       // group 1 q-row

        _Float16* Kl = smem;                          // [2][4096]
        _Float16* Vl = smem + 2 * 4096;               // [2][4096]

        const float*    Fcb = content + (size_t)b * Cc * HWs;
        const _Float16* Kb  = Kt + (size_t)b * HWs * Cc;
        const _Float16* Vb  = Vt + (size_t)b * Cc * HWs;

        const bool isK  = tid < 128;
        const int  sl   = tid & 127;
        const int  srow = sl >> 3;                    // 0..15 (+16i)
        const int  sjg  = sl & 7;                     // global 16B chunk in row
        const int  ssw  = (sjg ^ (srow & 7)) * 8;     // swizzled chunk offset (halfs)

        half8 qf[2][2];
        #pragma unroll
        for (int j = 0; j < 8; ++j) {
            qf[0][0][j] = (_Float16)(Fcb[(size_t)(quad * 8 + j) * HWs + qA] * RLOG2E);
            qf[0][1][j] = (_Float16)(Fcb[(size_t)(32 + quad * 8 + j) * HWs + qA] * RLOG2E);
            qf[1][0][j] = (_Float16)(Fcb[(size_t)(quad * 8 + j) * HWs + qB] * RLOG2E);
            qf[1][1][j] = (_Float16)(Fcb[(size_t)(32 + quad * 8 + j) * HWs + qB] * RLOG2E);
        }

        half8 st[4];
        auto stage_load = [&](int kt) {
            int kk0 = k0base + kt * 64;
            #pragma unroll
            for (int i = 0; i < 4; ++i) {
                int row = srow + 16 * i;
                if (isK) st[i] = *(const half8*)(Kb + (size_t)(kk0 + row) * 64 + sjg * 8);
                else     st[i] = *(const half8*)(Vb + (size_t)row * HWs + kk0 + sjg * 8);
            }
        };
        auto stage_write = [&](int p) {
            #pragma unroll
            for (int i = 0; i < 4; ++i) {
                int row = srow + 16 * i;
                if (isK) *(half8*)&Kl[p * 4096 + row * 64 + ssw] = st[i];
                else     *(half8*)&Vl[p * 4096 + row * 64 + ssw] = st[i];
            }
        };

        floatx4 acc[2][4];
        floatx4 accl[2];                              // SUM(P) via ones-A mfma
        #pragma unroll
        for (int g = 0; g < 2; ++g) {
            accl[g] = (floatx4)(0.0f);
            #pragma unroll
            for (int m = 0; m < 4; ++m) acc[g][m] = (floatx4)(0.0f);
        }
        float m_run[2] = {0.0f, 0.0f};                // init 0: combine shift-invariant

        half8 vone;
        #pragma unroll
        for (int j = 0; j < 8; ++j) vone[j] = (_Float16)1.0f;

        __syncthreads();                              // T-alias region dead; reuse as Kl/Vl
        stage_load(0);
        stage_write(0);
        stage_load(1);
        __syncthreads();

        const int swl = (l15 & 7);
        for (int kt = 0; kt < TILES_PER_SPLIT; ++kt) {
            const int p = kt & 1;
            if (kt + 1 < TILES_PER_SPLIT) stage_write(p ^ 1);
            if (kt + 2 < TILES_PER_SPLIT) stage_load(kt + 2);

            floatx4 sv[2][4];
            {
                floatx4 c0 = (floatx4)(-m_run[0]);
                floatx4 c1 = (floatx4)(-m_run[1]);
                #pragma unroll
                for (int m = 0; m < 4; ++m) {
                    const half8 ka0 = *(const half8*)&Kl[p * 4096 + (m * 16 + l15) * 64 + ((quad ^ swl) * 8)];
                    const half8 ka1 = *(const half8*)&Kl[p * 4096 + (m * 16 + l15) * 64 + (((4 + quad) ^ swl) * 8)];
                    sv[0][m] = __builtin_amdgcn_mfma_f32_16x16x32_f16(ka0, qf[0][0], c0, 0, 0, 0);
                    sv[0][m] = __builtin_amdgcn_mfma_f32_16x16x32_f16(ka1, qf[0][1], sv[0][m], 0, 0, 0);
                    sv[1][m] = __builtin_amdgcn_mfma_f32_16x16x32_f16(ka0, qf[1][0], c1, 0, 0, 0);
                    sv[1][m] = __builtin_amdgcn_mfma_f32_16x16x32_f16(ka1, qf[1][1], sv[1][m], 0, 0, 0);
                }
            }

            half8 va[4][2];
            #pragma unroll
            for (int m = 0; m < 4; ++m)
                #pragma unroll
                for (int ks = 0; ks < 2; ++ks)
                    va[m][ks] = *(const half8*)&Vl[p * 4096 + (m * 16 + l15) * 64 + (((ks * 4 + quad) ^ swl) * 8)];

            half8 pb[2][2];
            #pragma unroll
            for (int g = 0; g < 2; ++g) {
                float mm0 = fmaxf(fmaxf(fmaxf(sv[g][0][0], sv[g][0][1]), sv[g][0][2]), sv[g][0][3]);
                float mm1 = fmaxf(fmaxf(fmaxf(sv[g][1][0], sv[g][1][1]), sv[g][1][2]), sv[g][1][3]);
                float mm2 = fmaxf(fmaxf(fmaxf(sv[g][2][0], sv[g][2][1]), sv[g][2][2]), sv[g][2][3]);
                float mm3 = fmaxf(fmaxf(fmaxf(sv[g][3][0], sv[g][3][1]), sv[g][3][2]), sv[g][3][3]);
                float mx = fmaxf(fmaxf(fmaxf(mm0, mm1), mm2), mm3);   // = max(S) - m_old
                if (!__all(mx <= DEFER_THR)) {
                    unsigned mu = __float_as_uint(mx);
                    uint2v t32 = __builtin_amdgcn_permlane32_swap(mu, mu, false, false);
                    float wmx = fmaxf(__uint_as_float(t32[0]), __uint_as_float(t32[1]));
                    mu = __float_as_uint(wmx);
                    uint2v t16 = __builtin_amdgcn_permlane16_swap(mu, mu, false, false);
                    wmx = fmaxf(__uint_as_float(t16[0]), __uint_as_float(t16[1]));
                    float delta = fmaxf(wmx, 0.0f);       // wave-uniform growth
                    float alpha = EXP2(-delta);
                    m_run[g] += delta;
                    #pragma unroll
                    for (int m = 0; m < 4; ++m) acc[g][m] *= alpha;
                    accl[g] *= alpha;
                    #pragma unroll
                    for (int m = 0; m < 4; ++m)
                        #pragma unroll
                        for (int r = 0; r < 4; ++r) sv[g][m][r] -= delta;
                }
                unsigned Ap[4], Bp[4];
                #pragma unroll
                for (int m = 0; m < 4; ++m) {
                    float e0 = EXP2(sv[g][m][0]);
                    float e1 = EXP2(sv[g][m][1]);
                    float e2 = EXP2(sv[g][m][2]);
                    float e3 = EXP2(sv[g][m][3]);
                    Ap[m] = __builtin_bit_cast(unsigned, __builtin_amdgcn_cvt_pkrtz(e0, e1));
                    Bp[m] = __builtin_bit_cast(unsigned, __builtin_amdgcn_cvt_pkrtz(e2, e3));
                }
                unsigned pw[2][4];
                { uint2v a = __builtin_amdgcn_permlane32_swap(Ap[0], Ap[1], false, false);
                  uint2v u = __builtin_amdgcn_permlane16_swap(a[0], a[1], false, false);
                  pw[0][0] = u[0]; pw[0][2] = u[1]; }
                { uint2v a = __builtin_amdgcn_permlane32_swap(Bp[0], Bp[1], false, false);
                  uint2v u = __builtin_amdgcn_permlane16_swap(a[0], a[1], false, false);
                  pw[0][1] = u[0]; pw[0][3] = u[1]; }
                { uint2v a = __builtin_amdgcn_permlane32_swap(Ap[2], Ap[3], false, false);
                  uint2v u = __builtin_amdgcn_permlane16_swap(a[0], a[1], false, false);
                  pw[1][0] = u[0]; pw[1][2] = u[1]; }
                { uint2v a = __builtin_amdgcn_permlane32_swap(Bp[2], Bp[3], false, false);
                  uint2v u = __builtin_amdgcn_permlane16_swap(a[0], a[1], false, false);
                  pw[1][1] = u[0]; pw[1][3] = u[1]; }
                #pragma unroll
                for (int ks = 0; ks < 2; ++ks) {
                    union { unsigned u4[4]; half8 h; } z;
                    z.u4[0] = pw[ks][0]; z.u4[1] = pw[ks][1];
                    z.u4[2] = pw[ks][2]; z.u4[3] = pw[ks][3];
                    pb[g][ks] = z.h;
                }
            }

            #pragma unroll
            for (int m = 0; m < 4; ++m)
                #pragma unroll
                for (int g = 0; g < 2; ++g) {
                    acc[g][m] = __builtin_amdgcn_mfma_f32_16x16x32_f16(va[m][0], pb[g][0], acc[g][m], 0, 0, 0);
                    acc[g][m] = __builtin_amdgcn_mfma_f32_16x16x32_f16(va[m][1], pb[g][1], acc[g][m], 0, 0, 0);
                }
            accl[0] = __builtin_amdgcn_mfma_f32_16x16x32_f16(vone, pb[0][0], accl[0], 0, 0, 0);
            accl[0] = __builtin_amdgcn_mfma_f32_16x16x32_f16(vone, pb[0][1], accl[0], 0, 0, 0);
            accl[1] = __builtin_amdgcn_mfma_f32_16x16x32_f16(vone, pb[1][0], accl[1], 0, 0, 0);
            accl[1] = __builtin_amdgcn_mfma_f32_16x16x32_f16(vone, pb[1][1], accl[1], 0, 0, 0);

            __syncthreads();                          // one barrier per tile
        }

        _Float16* op = Opart + (((size_t)s * Bb + b) * Cc) * HWs;
        #pragma unroll
        for (int g = 0; g < 2; ++g) {
            int q = (g == 0) ? qA : qB;
            #pragma unroll
            for (int m = 0; m < 4; ++m)
                #pragma unroll
                for (int r = 0; r < 4; ++r) {
                    int c = m * 16 + quad * 4 + r;
                    op[(size_t)c * HWs + q] = (_Float16)acc[g][m][r];
                }
            if (quad == 0)
                ml[((size_t)b * HWs + q) * SPLITS + s] = make_float2(m_run[g], accl[g][0]);
        }
    }

    __threadfence();                                  // Opart/ml visible device-wide
    cg::this_grid().sync();

    // ---------- phase 3: combine (8 grid-stride iters)
    #pragma unroll
    for (int it = 0; it < 8; ++it)
        combine_body((it * 512 + bid) * 256 + tid, Opart, ml, out);
}

// ================= fallback kernels (R12-proven, verbatim) =================

__global__ __launch_bounds__(256) void prep_k(const float* __restrict__ content,
                                              const float* __restrict__ Fs,
                                              const float* __restrict__ Fst,
                                              float* __restrict__ out,
                                              _Float16* __restrict__ Kt,
                                              _Float16* __restrict__ Vt) {
    const int bid = blockIdx.x;
    const int t = threadIdx.x;
    if (bid < 1024) {
        prep_copy_body(bid * 256 + t, content, Fst, out, Vt);
    } else {
        __shared__ _Float16 T[16][72];
        int e = bid - 1024;                           // 0..1023
        int b = e >> 8;
        int hw0 = (e & 255) * 16;
        const float* sb = Fs + (size_t)b * Cc * HWs;
        {
            int c = t >> 2, x4 = (t & 3) * 4;         // 256 float4 = whole tile
            float4 v = *(const float4*)(sb + (size_t)c * HWs + hw0 + x4);
            T[x4 + 0][c] = (_Float16)v.x;
            T[x4 + 1][c] = (_Float16)v.y;
            T[x4 + 2][c] = (_Float16)v.z;
            T[x4 + 3][c] = (_Float16)v.w;
        }
        __syncthreads();
        if (t < 128) {
            int row = t >> 3, g = t & 7;
            _Float16* db = Kt + (size_t)b * HWs * Cc;
            *(half8*)(db + (size_t)(hw0 + row) * Cc + g * 8) = *(half8*)&T[row][g * 8];
        }
    }
}

__global__ __launch_bounds__(256, 2) void attn_k(const float* __restrict__ Fc,
                                                 const _Float16* __restrict__ Kt,
                                                 const _Float16* __restrict__ Vt,
                                                 _Float16* __restrict__ Opart,
                                                 float2* __restrict__ ml) {
    const int tid  = threadIdx.x;                 // 0..255
    const int lane = tid & 63;
    const int quad = lane >> 4;
    const int l15  = lane & 15;
    const int w    = tid >> 6;                    // wave 0..3
    const int qg = blockIdx.x & 31;
    const int b  = (blockIdx.x >> 5) & 3;
    const int s  = blockIdx.x >> 7;
    const int k0base = s * TILES_PER_SPLIT * 64;
    const int qA = qg * 128 + w * 32 + l15;       // group 0 q-row
    const int qB = qA + 16;                       // group 1 q-row

    __shared__ _Float16 Kl[2][64 * 64];
    __shared__ _Float16 Vl[2][64 * 64];

    const float*    Fcb = Fc + (size_t)b * Cc * HWs;
    const _Float16* Kb  = Kt + (size_t)b * HWs * Cc;
    const _Float16* Vb  = Vt + (size_t)b * Cc * HWs;

    const bool isK  = tid < 128;
    const int  sl   = tid & 127;
    const int  srow = sl >> 3;                    // 0..15 (+16i)
    const int  sjg  = sl & 7;                     // global 16B chunk in row
    const int  ssw  = (sjg ^ (srow & 7)) * 8;     // swizzled chunk offset (halfs)

    half8 qf[2][2];
    #pragma unroll
    for (int j = 0; j < 8; ++j) {
        qf[0][0][j] = (_Float16)(Fcb[(size_t)(quad * 8 + j) * HWs + qA] * RLOG2E);
        qf[0][1][j] = (_Float16)(Fcb[(size_t)(32 + quad * 8 + j) * HWs + qA] * RLOG2E);
        qf[1][0][j] = (_Float16)(Fcb[(size_t)(quad * 8 + j) * HWs + qB] * RLOG2E);
        qf[1][1][j] = (_Float16)(Fcb[(size_t)(32 + quad * 8 + j) * HWs + qB] * RLOG2E);
    }

    half8 st[4];
    auto stage_load = [&](int kt) {
        int kk0 = k0base + kt * 64;
        #pragma unroll
        for (int i = 0; i < 4; ++i) {
            int row = srow + 16 * i;
            if (isK) st[i] = *(const half8*)(Kb + (size_t)(kk0 + row) * 64 + sjg * 8);
            else     st[i] = *(const half8*)(Vb + (size_t)row * HWs + kk0 + sjg * 8);
        }
    };
    auto stage_write = [&](int p) {
        #pragma unroll
        for (int i = 0; i < 4; ++i) {
            int row = srow + 16 * i;
            if (isK) *(half8*)&Kl[p][row * 64 + ssw] = st[i];
            else     *(half8*)&Vl[p][row * 64 + ssw] = st[i];
        }
    };

    floatx4 acc[2][4];
    floatx4 accl[2];                              // SUM(P) via ones-A mfma
    #pragma unroll
    for (int g = 0; g < 2; ++g) {
        accl[g] = (floatx4)(0.0f);
        #pragma unroll
        for (int m = 0; m < 4; ++m) acc[g][m] = (floatx4)(0.0f);
    }
    float m_run[2] = {0.0f, 0.0f};                // init 0: combine is shift-invariant

    half8 vone;
    #pragma unroll
    for (int j = 0; j < 8; ++j) vone[j] = (_Float16)1.0f;

    stage_load(0);
    stage_write(0);
    stage_load(1);
    __syncthreads();

    const int swl = (l15 & 7);
    for (int kt = 0; kt < TILES_PER_SPLIT; ++kt) {
        const int p = kt & 1;
        if (kt + 1 < TILES_PER_SPLIT) stage_write(p ^ 1);
        if (kt + 2 < TILES_PER_SPLIT) stage_load(kt + 2);

        floatx4 sv[2][4];
        {
            floatx4 c0 = (floatx4)(-m_run[0]);
            floatx4 c1 = (floatx4)(-m_run[1]);
            #pragma unroll
            for (int m = 0; m < 4; ++m) {
                const half8 ka0 = *(const half8*)&Kl[p][(m * 16 + l15) * 64 + ((quad ^ swl) * 8)];
                const half8 ka1 = *(const half8*)&Kl[p][(m * 16 + l15) * 64 + (((4 + quad) ^ swl) * 8)];
                sv[0][m] = __builtin_amdgcn_mfma_f32_16x16x32_f16(ka0, qf[0][0], c0, 0, 0, 0);
                sv[0][m] = __builtin_amdgcn_mfma_f32_16x16x32_f16(ka1, qf[0][1], sv[0][m], 0, 0, 0);
                sv[1][m] = __builtin_amdgcn_mfma_f32_16x16x32_f16(ka0, qf[1][0], c1, 0, 0, 0);
                sv[1][m] = __builtin_amdgcn_mfma_f32_16x16x32_f16(ka1, qf[1][1], sv[1][m], 0, 0, 0);
            }
        }

        half8 va[4][2];
        #pragma unroll
        for (int m = 0; m < 4; ++m)
            #pragma unroll
            for (int ks = 0; ks < 2; ++ks)
                va[m][ks] = *(const half8*)&Vl[p][(m * 16 + l15) * 64 + (((ks * 4 + quad) ^ swl) * 8)];

        half8 pb[2][2];
        #pragma unroll
        for (int g = 0; g < 2; ++g) {
            float mm0 = fmaxf(fmaxf(fmaxf(sv[g][0][0], sv[g][0][1]), sv[g][0][2]), sv[g][0][3]);
            float mm1 = fmaxf(fmaxf(fmaxf(sv[g][1][0], sv[g][1][1]), sv[g][1][2]), sv[g][1][3]);
            float mm2 = fmaxf(fmaxf(fmaxf(sv[g][2][0], sv[g][2][1]), sv[g][2][2]), sv[g][2][3]);
            float mm3 = fmaxf(fmaxf(fmaxf(sv[g][3][0], sv[g][3][1]), sv[g][3][2]), sv[g][3][3]);
            float mx = fmaxf(fmaxf(fmaxf(mm0, mm1), mm2), mm3);   // = max(S) - m_old
            if (!__all(mx <= DEFER_THR)) {
                unsigned mu = __float_as_uint(mx);
                uint2v t32 = __builtin_amdgcn_permlane32_swap(mu, mu, false, false);
                float wmx = fmaxf(__uint_as_float(t32[0]), __uint_as_float(t32[1]));
                mu = __float_as_uint(wmx);
                uint2v t16 = __builtin_amdgcn_permlane16_swap(mu, mu, false, false);
                wmx = fmaxf(__uint_as_float(t16[0]), __uint_as_float(t16[1]));
                float delta = fmaxf(wmx, 0.0f);       // wave-uniform growth
                float alpha = EXP2(-delta);
                m_run[g] += delta;
                #pragma unroll
                for (int m = 0; m < 4; ++m) acc[g][m] *= alpha;
                accl[g] *= alpha;
                #pragma unroll
                for (int m = 0; m < 4; ++m)
                    #pragma unroll
                    for (int r = 0; r < 4; ++r) sv[g][m][r] -= delta;
            }
            unsigned Ap[4], Bp[4];
            #pragma unroll
            for (int m = 0; m < 4; ++m) {
                float e0 = EXP2(sv[g][m][0]);
                float e1 = EXP2(sv[g][m][1]);
                float e2 = EXP2(sv[g][m][2]);
                float e3 = EXP2(sv[g][m][3]);
                Ap[m] = __builtin_bit_cast(unsigned, __builtin_amdgcn_cvt_pkrtz(e0, e1));
                Bp[m] = __builtin_bit_cast(unsigned, __builtin_amdgcn_cvt_pkrtz(e2, e3));
            }
            unsigned pw[2][4];
            { uint2v a = __builtin_amdgcn_permlane32_swap(Ap[0], Ap[1], false, false);
              uint2v u = __builtin_amdgcn_permlane16_swap(a[0], a[1], false, false);
              pw[0][0] = u[0]; pw[0][2] = u[1]; }
            { uint2v a = __builtin_amdgcn_permlane32_swap(Bp[0], Bp[1], false, false);
              uint2v u = __builtin_amdgcn_permlane16_swap(a[0], a[1], false, false);
              pw[0][1] = u[0]; pw[0][3] = u[1]; }
            { uint2v a = __builtin_amdgcn_permlane32_swap(Ap[2], Ap[3], false, false);
              uint2v u = __builtin_amdgcn_permlane16_swap(a[0], a[1], false, false);
              pw[1][0] = u[0]; pw[1][2] = u[1]; }
            { uint2v a = __builtin_amdgcn_permlane32_swap(Bp[2], Bp[3], false, false);
              uint2v u = __builtin_amdgcn_permlane16_swap(a[0], a[1], false, false);
              pw[1][1] = u[0]; pw[1][3] = u[1]; }
            #pragma unroll
            for (int ks = 0; ks < 2; ++ks) {
                union { unsigned u4[4]; half8 h; } z;
                z.u4[0] = pw[ks][0]; z.u4[1] = pw[ks][1];
                z.u4[2] = pw[ks][2]; z.u4[3] = pw[ks][3];
                pb[g][ks] = z.h;
            }
        }

        #pragma unroll
        for (int m = 0; m < 4; ++m)
            #pragma unroll
            for (int g = 0; g < 2; ++g) {
                acc[g][m] = __builtin_amdgcn_mfma_f32_16x16x32_f16(va[m][0], pb[g][0], acc[g][m], 0, 0, 0);
                acc[g][m] = __builtin_amdgcn_mfma_f32_16x16x32_f16(va[m][1], pb[g][1], acc[g][m], 0, 0, 0);
            }
        accl[0] = __builtin_amdgcn_mfma_f32_16x16x32_f16(vone, pb[0][0], accl[0], 0, 0, 0);
        accl[0] = __builtin_amdgcn_mfma_f32_16x16x32_f16(vone, pb[0][1], accl[0], 0, 0, 0);
        accl[1] = __builtin_amdgcn_mfma_f32_16x16x32_f16(vone, pb[1][0], accl[1], 0, 0, 0);
        accl[1] = __builtin_amdgcn_mfma_f32_16x16x32_f16(vone, pb[1][1], accl[1], 0, 0, 0);

        __syncthreads();                          // one barrier per tile
    }

    _Float16* op = Opart + (((size_t)s * Bb + b) * Cc) * HWs;
    #pragma unroll
    for (int g = 0; g < 2; ++g) {
        int q = (g == 0) ? qA : qB;
        #pragma unroll
        for (int m = 0; m < 4; ++m)
            #pragma unroll
            for (int r = 0; r < 4; ++r) {
                int c = m * 16 + quad * 4 + r;
                op[(size_t)c * HWs + q] = (_Float16)acc[g][m][r];
            }
        if (quad == 0)
            ml[((size_t)b * HWs + q) * SPLITS + s] = make_float2(m_run[g], accl[g][0]);
    }
}

__global__ __launch_bounds__(256) void combine_k(const _Float16* __restrict__ Opart,
                                                 const float2* __restrict__ ml,
                                                 float* __restrict__ out) {
    combine_body(blockIdx.x * 256 + threadIdx.x, Opart, ml, out);
}

// ================= host =================

extern "C" void kernel_launch(void* const* d_in, const int* in_sizes, int n_in,
                              void* d_out, int out_size, void* d_ws, size_t ws_size,
                              hipStream_t stream) {
    const float* content   = (const float*)d_in[0];
    const float* content_s = (const float*)d_in[1];
    const float* style     = (const float*)d_in[2];
    float* out = (float*)d_out;

    _Float16* Kt = (_Float16*)d_ws;                           // [4][4096][64] f16  (2 MB)
    _Float16* Vt = Kt + (size_t)Bb * HWs * Cc;                // [4][64][4096] f16  (2 MB)
    _Float16* Opart = Vt + (size_t)Bb * Cc * HWs;             // [SPLITS][4][64][4096] f16 (8.4 MB)
    float2*   ml = (float2*)(Opart + (size_t)SPLITS * Bb * Cc * HWs);  // [4][4096][SPLITS]

    // try the fused cooperative path; fall back to the proven 3-kernel path
    void* args[] = { (void*)&content, (void*)&content_s, (void*)&style, (void*)&out,
                     (void*)&Kt, (void*)&Vt, (void*)&Opart, (void*)&ml };
    hipError_t err = hipLaunchCooperativeKernel((const void*)fused_k, dim3(512), dim3(256),
                                                args, 0, stream);
    if (err != hipSuccess) {
        (void)hipGetLastError();                  // clear sticky error
        prep_k<<<dim3(2048), dim3(256), 0, stream>>>(content, content_s, style, out, Kt, Vt);
        attn_k<<<dim3(SPLITS * Bb * 32), dim3(256), 0, stream>>>(content, Kt, Vt, Opart, ml);
        combine_k<<<dim3(4096), dim3(256), 0, stream>>>(Opart, ml, out);
    }
}

// Round 16
// 99.953 us; speedup vs baseline: 2.9581x; 2.9581x over previous
//
#include <hip/hip_runtime.h>
#include <math.h>

// SANet attention: MFMA flash, LDS-staged K/V (xor-swizzled), 32 q-rows/wave,
// split-K=4, f16 partials. b=4, c=64, HW=4096, fp32 in/out.
//
// R19 = R12/R17 EXACT (twice-benched best: 100.58 / 100.19 us). R18's
// cooperative fusion regressed 3x (fused_k 227us: grid.sync spin-wait across
// 8 XCDs is tens of us per sync, and in-kernel serialization forfeits
// stream-level overlap) -> fusion axis closed, reverted.
//
// Session summary (15 data points): only the instruction diet paid (R12,
// -11.7us vs 110.1 baseline). Closed axes: scheduling (R9/R10 flat),
// occupancy 2/3/4 blocks/CU (R7/R13/R15), LDS-volume halving (R14), no-LDS
// (R11 -52%), combine micro-opt (R16), cooperative fusion (R18 -195%).
// attn ~33us is dependency-stall-bound (MfmaUtil 14%, VALUBusy 49%, HBM 8%):
// serial softmax chain (max -> permlane -> exp2 quarter-rate -> cvt ->
// permlane -> PV) over only ~17 GFLOP of MFMA work. Fill ~45us is harness
// workspace poison; prep+combine+gaps ~22us with no >=2us lever identified.
//
// Diet (R12-proven): raw v_exp2, m-in-MFMA-C (m_run init 0, combine is
// shift-invariant), permlane P-redistribution (no Ps LDS roundtrip),
// ones-MFMA lsum, left-deep max chains. LB(256,2).
//
// mfma_f32_16x16x32_f16: A[m=lane&15][k=quad*8+j], B[k=quad*8+j][n=lane&15],
// D[m=quad*4+reg][n=lane&15]  (quad = lane>>4).
// S-mfma computes S^T tile (m=k_key, n=q); PV computes O^T (m=c, n=q).
// P redistribution (R7-verified): A_m=pk(sv[m][0],sv[m][1]),
// B_m=pk(sv[m][2],sv[m][3]); (w0,w2)=pl16swap(pl32swap(A_L,A_H)); (w1,w3) from B.

#define Bb 4
#define Cc 64
#define HWs 4096
#define SPLITS 4
#define TILES_PER_SPLIT 16      // 1024 k per split / 64
#define RLOG2E 1.44269504088896340736f
#define DEFER_THR 6.0f

typedef _Float16 half8 __attribute__((ext_vector_type(8)));
typedef _Float16 half4 __attribute__((ext_vector_type(4)));
typedef float floatx4 __attribute__((ext_vector_type(4)));
typedef unsigned uint2v __attribute__((ext_vector_type(2)));

extern "C" __device__ float __ocml_native_exp2_f32(float);
#if defined(__has_builtin) && __has_builtin(__builtin_amdgcn_exp2f)
#define EXP2(x) __builtin_amdgcn_exp2f(x)
#else
#define EXP2(x) __ocml_native_exp2_f32(x)
#endif

// ---------------- prep: content copy + Vt convert + Kt transpose ----------------
__global__ __launch_bounds__(256) void prep_k(const float* __restrict__ content,
                                              const float* __restrict__ Fs,
                                              const float* __restrict__ Fst,
                                              float* __restrict__ out,
                                              _Float16* __restrict__ Kt,
                                              _Float16* __restrict__ Vt) {
    const int bid = blockIdx.x;
    const int t = threadIdx.x;
    if (bid < 1024) {
        // content copy (float4) + V f16 convert (same linear layout)
        int i4 = bid * 256 + t;                       // 0..262143
        const float4* c4 = (const float4*)content;
        const float4* v4 = (const float4*)Fst;
        float4* o4 = (float4*)out;
        int b = i4 >> 16, rem = i4 & 65535;
        o4[(size_t)b * 131072 + rem] = c4[i4];        // out batch stride 2*64*4096 f32
        float4 v = v4[i4];
        half4 h;
        h[0] = (_Float16)v.x; h[1] = (_Float16)v.y;
        h[2] = (_Float16)v.z; h[3] = (_Float16)v.w;
        *(half4*)(Vt + (size_t)i4 * 4) = h;
    } else {
        // transpose+convert one 16hw x 64c tile of Fs -> Kt[b][k][c]
        __shared__ _Float16 T[16][72];
        int e = bid - 1024;                           // 0..1023
        int b = e >> 8;
        int hw0 = (e & 255) * 16;
        const float* sb = Fs + (size_t)b * Cc * HWs;
        {
            int c = t >> 2, x4 = (t & 3) * 4;         // 256 float4 = whole tile
            float4 v = *(const float4*)(sb + (size_t)c * HWs + hw0 + x4);
            T[x4 + 0][c] = (_Float16)v.x;
            T[x4 + 1][c] = (_Float16)v.y;
            T[x4 + 2][c] = (_Float16)v.z;
            T[x4 + 3][c] = (_Float16)v.w;
        }
        __syncthreads();
        if (t < 128) {
            int row = t >> 3, g = t & 7;
            _Float16* db = Kt + (size_t)b * HWs * Cc;
            *(half8*)(db + (size_t)(hw0 + row) * Cc + g * 8) = *(half8*)&T[row][g * 8];
        }
    }
}

// ---------------- attn: flash, LDS tiles, 32 q/wave, instruction-diet (R12 exact) ----------------
__global__ __launch_bounds__(256, 2) void attn_k(const float* __restrict__ Fc,
                                                 const _Float16* __restrict__ Kt,
                                                 const _Float16* __restrict__ Vt,
                                                 _Float16* __restrict__ Opart,
                                                 float2* __restrict__ ml) {
    const int tid  = threadIdx.x;                 // 0..255
    const int lane = tid & 63;
    const int quad = lane >> 4;
    const int l15  = lane & 15;
    const int w    = tid >> 6;                    // wave 0..3
    // block: [split][b][qgroup]
    const int qg = blockIdx.x & 31;
    const int b  = (blockIdx.x >> 5) & 3;
    const int s  = blockIdx.x >> 7;
    const int k0base = s * TILES_PER_SPLIT * 64;
    const int qA = qg * 128 + w * 32 + l15;       // group 0 q-row
    const int qB = qA + 16;                       // group 1 q-row

    // xor-swizzled tiles: 16B chunk j of row r stored at chunk j^(r&7)
    __shared__ _Float16 Kl[2][64 * 64];
    __shared__ _Float16 Vl[2][64 * 64];

    const float*    Fcb = Fc + (size_t)b * Cc * HWs;
    const _Float16* Kb  = Kt + (size_t)b * HWs * Cc;
    const _Float16* Vb  = Vt + (size_t)b * Cc * HWs;

    // staging role: tids 0..127 stage K, 128..255 stage V; 4 chunks each
    const bool isK  = tid < 128;
    const int  sl   = tid & 127;
    const int  srow = sl >> 3;                    // 0..15 (+16i)
    const int  sjg  = sl & 7;                     // global 16B chunk in row
    const int  ssw  = (sjg ^ (srow & 7)) * 8;     // swizzled chunk offset (halfs)

    // Q B-frags from fp32 Fc, pre-scaled by log2e (one-time strided loads)
    half8 qf[2][2];
    #pragma unroll
    for (int j = 0; j < 8; ++j) {
        qf[0][0][j] = (_Float16)(Fcb[(size_t)(quad * 8 + j) * HWs + qA] * RLOG2E);
        qf[0][1][j] = (_Float16)(Fcb[(size_t)(32 + quad * 8 + j) * HWs + qA] * RLOG2E);
        qf[1][0][j] = (_Float16)(Fcb[(size_t)(quad * 8 + j) * HWs + qB] * RLOG2E);
        qf[1][1][j] = (_Float16)(Fcb[(size_t)(32 + quad * 8 + j) * HWs + qB] * RLOG2E);
    }

    half8 st[4];
    auto stage_load = [&](int kt) {
        int kk0 = k0base + kt * 64;
        #pragma unroll
        for (int i = 0; i < 4; ++i) {
            int row = srow + 16 * i;
            if (isK) st[i] = *(const half8*)(Kb + (size_t)(kk0 + row) * 64 + sjg * 8);
            else     st[i] = *(const half8*)(Vb + (size_t)row * HWs + kk0 + sjg * 8);
        }
    };
    auto stage_write = [&](int p) {
        #pragma unroll
        for (int i = 0; i < 4; ++i) {
            int row = srow + 16 * i;
            if (isK) *(half8*)&Kl[p][row * 64 + ssw] = st[i];
            else     *(half8*)&Vl[p][row * 64 + ssw] = st[i];
        }
    };

    floatx4 acc[2][4];
    floatx4 accl[2];                              // SUM(P) via ones-A mfma
    #pragma unroll
    for (int g = 0; g < 2; ++g) {
        accl[g] = (floatx4)(0.0f);
        #pragma unroll
        for (int m = 0; m < 4; ++m) acc[g][m] = (floatx4)(0.0f);
    }
    float m_run[2] = {0.0f, 0.0f};                // init 0: combine is shift-invariant

    half8 vone;
    #pragma unroll
    for (int j = 0; j < 8; ++j) vone[j] = (_Float16)1.0f;

    stage_load(0);
    stage_write(0);
    stage_load(1);
    __syncthreads();

    const int swl = (l15 & 7);
    for (int kt = 0; kt < TILES_PER_SPLIT; ++kt) {
        const int p = kt & 1;
        if (kt + 1 < TILES_PER_SPLIT) stage_write(p ^ 1);
        if (kt + 2 < TILES_PER_SPLIT) stage_load(kt + 2);

        // K A-frags + S-MFMA, C seeded with -m_run => sv = S - m_old directly
        floatx4 sv[2][4];
        {
            floatx4 c0 = (floatx4)(-m_run[0]);
            floatx4 c1 = (floatx4)(-m_run[1]);
            #pragma unroll
            for (int m = 0; m < 4; ++m) {
                const half8 ka0 = *(const half8*)&Kl[p][(m * 16 + l15) * 64 + ((quad ^ swl) * 8)];
                const half8 ka1 = *(const half8*)&Kl[p][(m * 16 + l15) * 64 + (((4 + quad) ^ swl) * 8)];
                sv[0][m] = __builtin_amdgcn_mfma_f32_16x16x32_f16(ka0, qf[0][0], c0, 0, 0, 0);
                sv[0][m] = __builtin_amdgcn_mfma_f32_16x16x32_f16(ka1, qf[0][1], sv[0][m], 0, 0, 0);
                sv[1][m] = __builtin_amdgcn_mfma_f32_16x16x32_f16(ka0, qf[1][0], c1, 0, 0, 0);
                sv[1][m] = __builtin_amdgcn_mfma_f32_16x16x32_f16(ka1, qf[1][1], sv[1][m], 0, 0, 0);
            }
        }

        // V A-frags (issued early; consumed after softmax)
        half8 va[4][2];
        #pragma unroll
        for (int m = 0; m < 4; ++m)
            #pragma unroll
            for (int ks = 0; ks < 2; ++ks)
                va[m][ks] = *(const half8*)&Vl[p][(m * 16 + l15) * 64 + (((ks * 4 + quad) ^ swl) * 8)];

        // online softmax per q-group (log2 domain); sv already = S - m_old
        half8 pb[2][2];
        #pragma unroll
        for (int g = 0; g < 2; ++g) {
            // left-deep chains (v_max3-fusable): per-m then combine
            float mm0 = fmaxf(fmaxf(fmaxf(sv[g][0][0], sv[g][0][1]), sv[g][0][2]), sv[g][0][3]);
            float mm1 = fmaxf(fmaxf(fmaxf(sv[g][1][0], sv[g][1][1]), sv[g][1][2]), sv[g][1][3]);
            float mm2 = fmaxf(fmaxf(fmaxf(sv[g][2][0], sv[g][2][1]), sv[g][2][2]), sv[g][2][3]);
            float mm3 = fmaxf(fmaxf(fmaxf(sv[g][3][0], sv[g][3][1]), sv[g][3][2]), sv[g][3][3]);
            float mx = fmaxf(fmaxf(fmaxf(mm0, mm1), mm2), mm3);   // = max(S) - m_old
            // defer-max: rescale only when some lane grew past THR (P <= 2^THR)
            if (!__all(mx <= DEFER_THR)) {
                unsigned mu = __float_as_uint(mx);
                uint2v t32 = __builtin_amdgcn_permlane32_swap(mu, mu, false, false);
                float wmx = fmaxf(__uint_as_float(t32[0]), __uint_as_float(t32[1]));
                mu = __float_as_uint(wmx);
                uint2v t16 = __builtin_amdgcn_permlane16_swap(mu, mu, false, false);
                wmx = fmaxf(__uint_as_float(t16[0]), __uint_as_float(t16[1]));
                float delta = fmaxf(wmx, 0.0f);       // wave-uniform growth
                float alpha = EXP2(-delta);
                m_run[g] += delta;
                #pragma unroll
                for (int m = 0; m < 4; ++m) acc[g][m] *= alpha;
                accl[g] *= alpha;
                #pragma unroll
                for (int m = 0; m < 4; ++m)
                    #pragma unroll
                    for (int r = 0; r < 4; ++r) sv[g][m][r] -= delta;
            }
            unsigned Ap[4], Bp[4];
            #pragma unroll
            for (int m = 0; m < 4; ++m) {
                float e0 = EXP2(sv[g][m][0]);
                float e1 = EXP2(sv[g][m][1]);
                float e2 = EXP2(sv[g][m][2]);
                float e3 = EXP2(sv[g][m][3]);
                Ap[m] = __builtin_bit_cast(unsigned, __builtin_amdgcn_cvt_pkrtz(e0, e1));
                Bp[m] = __builtin_bit_cast(unsigned, __builtin_amdgcn_cvt_pkrtz(e2, e3));
            }
            // D-layout -> B-layout across quads: 2 swaps per word-pair
            unsigned pw[2][4];
            { uint2v a = __builtin_amdgcn_permlane32_swap(Ap[0], Ap[1], false, false);
              uint2v u = __builtin_amdgcn_permlane16_swap(a[0], a[1], false, false);
              pw[0][0] = u[0]; pw[0][2] = u[1]; }
            { uint2v a = __builtin_amdgcn_permlane32_swap(Bp[0], Bp[1], false, false);
              uint2v u = __builtin_amdgcn_permlane16_swap(a[0], a[1], false, false);
              pw[0][1] = u[0]; pw[0][3] = u[1]; }
            { uint2v a = __builtin_amdgcn_permlane32_swap(Ap[2], Ap[3], false, false);
              uint2v u = __builtin_amdgcn_permlane16_swap(a[0], a[1], false, false);
              pw[1][0] = u[0]; pw[1][2] = u[1]; }
            { uint2v a = __builtin_amdgcn_permlane32_swap(Bp[2], Bp[3], false, false);
              uint2v u = __builtin_amdgcn_permlane16_swap(a[0], a[1], false, false);
              pw[1][1] = u[0]; pw[1][3] = u[1]; }
            #pragma unroll
            for (int ks = 0; ks < 2; ++ks) {
                union { unsigned u4[4]; half8 h; } z;
                z.u4[0] = pw[ks][0]; z.u4[1] = pw[ks][1];
                z.u4[2] = pw[ks][2]; z.u4[3] = pw[ks][3];
                pb[g][ks] = z.h;
            }
        }

        // O^T update: D[m=c][n=q] + lsum on the matrix pipe
        #pragma unroll
        for (int m = 0; m < 4; ++m)
            #pragma unroll
            for (int g = 0; g < 2; ++g) {
                acc[g][m] = __builtin_amdgcn_mfma_f32_16x16x32_f16(va[m][0], pb[g][0], acc[g][m], 0, 0, 0);
                acc[g][m] = __builtin_amdgcn_mfma_f32_16x16x32_f16(va[m][1], pb[g][1], acc[g][m], 0, 0, 0);
            }
        accl[0] = __builtin_amdgcn_mfma_f32_16x16x32_f16(vone, pb[0][0], accl[0], 0, 0, 0);
        accl[0] = __builtin_amdgcn_mfma_f32_16x16x32_f16(vone, pb[0][1], accl[0], 0, 0, 0);
        accl[1] = __builtin_amdgcn_mfma_f32_16x16x32_f16(vone, pb[1][0], accl[1], 0, 0, 0);
        accl[1] = __builtin_amdgcn_mfma_f32_16x16x32_f16(vone, pb[1][1], accl[1], 0, 0, 0);

        __syncthreads();                          // one barrier per tile
    }

    // write partials (f16) + (M,l); lsum from accl (row-sum already complete)
    _Float16* op = Opart + (((size_t)s * Bb + b) * Cc) * HWs;
    #pragma unroll
    for (int g = 0; g < 2; ++g) {
        int q = (g == 0) ? qA : qB;
        #pragma unroll
        for (int m = 0; m < 4; ++m)
            #pragma unroll
            for (int r = 0; r < 4; ++r) {
                int c = m * 16 + quad * 4 + r;
                op[(size_t)c * HWs + q] = (_Float16)acc[g][m][r];
            }
        if (quad == 0)
            ml[((size_t)b * HWs + q) * SPLITS + s] = make_float2(m_run[g], accl[g][0]);
    }
}

// ---------------- combine: merge splits (exp2 domain) ----------------
__global__ __launch_bounds__(256) void combine_k(const _Float16* __restrict__ Opart,
                                                 const float2* __restrict__ ml,
                                                 float* __restrict__ out) {
    int idx = blockIdx.x * 256 + threadIdx.x;     // over 4*64*4096 = 1M
    int q = idx & 4095;
    int c = (idx >> 12) & 63;
    int b = idx >> 18;
    const float2* mlp = ml + ((size_t)b * HWs + q) * SPLITS;
    float2 mls[SPLITS];
    #pragma unroll
    for (int s = 0; s < SPLITS; ++s) mls[s] = mlp[s];
    float M = -INFINITY;
    #pragma unroll
    for (int s = 0; s < SPLITS; ++s) M = fmaxf(M, mls[s].x);
    float l = 0.0f, o = 0.0f;
    #pragma unroll
    for (int s = 0; s < SPLITS; ++s) {
        float wgt = EXP2(mls[s].x - M);
        l += wgt * mls[s].y;
        o += wgt * (float)Opart[(((size_t)s * Bb + b) * Cc + c) * HWs + q];
    }
    out[((size_t)b * 2 * Cc + Cc + c) * HWs + q] = o / l;
}

extern "C" void kernel_launch(void* const* d_in, const int* in_sizes, int n_in,
                              void* d_out, int out_size, void* d_ws, size_t ws_size,
                              hipStream_t stream) {
    const float* content   = (const float*)d_in[0];
    const float* content_s = (const float*)d_in[1];
    const float* style     = (const float*)d_in[2];
    float* out = (float*)d_out;

    _Float16* Kt = (_Float16*)d_ws;                           // [4][4096][64] f16  (2 MB)
    _Float16* Vt = Kt + (size_t)Bb * HWs * Cc;                // [4][64][4096] f16  (2 MB)
    _Float16* Opart = Vt + (size_t)Bb * Cc * HWs;             // [SPLITS][4][64][4096] f16 (8.4 MB)
    float2*   ml = (float2*)(Opart + (size_t)SPLITS * Bb * Cc * HWs);  // [4][4096][SPLITS]

    prep_k<<<dim3(2048), dim3(256), 0, stream>>>(content, content_s, style, out, Kt, Vt);
    attn_k<<<dim3(SPLITS * Bb * 32), dim3(256), 0, stream>>>(content, Kt, Vt, Opart, ml);
    combine_k<<<dim3(4096), dim3(256), 0, stream>>>(Opart, ml, out);
}